// Round 2
// baseline (694.436 us; speedup 1.0000x reference)
//
#include <hip/hip_runtime.h>
#include <hip/hip_fp16.h>
#include <stdint.h>

#define B_SZ 32
#define S_SZ 2048
#define H_SZ 1024
#define M_SZ (B_SZ * S_SZ)

typedef _Float16 half8 __attribute__((ext_vector_type(8)));
typedef float floatx4 __attribute__((ext_vector_type(4)));

struct h4 { _Float16 x, y, z, w; };

// ---------------- Wk fp32 -> fp16 (tiny, 4 MB -> 2 MB) ----------------
__global__ __launch_bounds__(256) void convert_f32_to_f16(
    const float* __restrict__ in, h4* __restrict__ out, int n4) {
  int i = blockIdx.x * blockDim.x + threadIdx.x;
  int stride = gridDim.x * blockDim.x;
  const float4* in4 = (const float4*)in;
  for (; i < n4; i += stride) {
    float4 f = in4[i];
    h4 o;
    o.x = (_Float16)f.x; o.y = (_Float16)f.y;
    o.z = (_Float16)f.z; o.w = (_Float16)f.w;
    out[i] = o;
  }
}

// ---------------- query = hidden @ Wq^T, one wave per output ----------------
__global__ __launch_bounds__(256) void query_kernel(
    const float* __restrict__ hidden, const float* __restrict__ Wq,
    float* __restrict__ q) {
  const int W = blockIdx.x * 4 + (threadIdx.x >> 6);   // 32768 waves
  const int lane = threadIdx.x & 63;
  const int b = W >> 10;
  const int n = W & 1023;
  const float4* hp = (const float4*)(hidden + (size_t)b * H_SZ);
  const float4* wp = (const float4*)(Wq + (size_t)n * H_SZ);
  float acc = 0.f;
  #pragma unroll
  for (int i = 0; i < 4; ++i) {
    float4 h = hp[lane + 64 * i];
    float4 w = wp[lane + 64 * i];
    acc = fmaf(h.x, w.x, acc);
    acc = fmaf(h.y, w.y, acc);
    acc = fmaf(h.z, w.z, acc);
    acc = fmaf(h.w, w.w, acc);
  }
  #pragma unroll
  for (int off = 32; off; off >>= 1) acc += __shfl_xor(acc, off);
  if (lane == 0) q[(size_t)b * H_SZ + n] = acc;
}

// ---------------- async global->LDS, 16B/lane ----------------
__device__ __forceinline__ void gl_lds16(const void* g, void* l) {
  __builtin_amdgcn_global_load_lds(
      (const __attribute__((address_space(1))) void*)g,
      (__attribute__((address_space(3))) void*)l,
      16, 0, 0);
}

__device__ __forceinline__ float fast_tanh(float x) {
  float ax = fabsf(x);
  float e = __expf(ax * -2.0f);
  float t = (1.0f - e) / (1.0f + e);
  return copysignf(t, x);
}

// ---------------- fused fp32-load GEMM + tanh + v-dot ----------------
// A = enc (fp32, staged to LDS as fp32, converted at frag-load), Bt = Wk fp16.
// LDS layouts are FRAGMENT-MAJOR (conflict-free ds_read_b128):
//   A byte pos = wm*8192 + m*2048 + half*1024 + lane*16   (fp32, 16 KB)
//   B byte pos = wn*4096 + n*1024  + lane*16              (fp16,  8 KB)
// Staging permutes per-lane GLOBAL source addresses to match (address set per
// issue is identical to the natural pattern -> same coalescing).
#define TILE 128
#define BK 32

__global__ __launch_bounds__(256) void fused_keys_kernel(
    const float* __restrict__ A,       // M_SZ x H_SZ fp32 (enc)
    const _Float16* __restrict__ Bt,   // H_SZ x H_SZ fp16 (Wk)
    const float* __restrict__ q,       // B_SZ x H_SZ fp32
    const float* __restrict__ v,       // H_SZ fp32
    float* __restrict__ partial)       // 8 x M_SZ
{
  __shared__ float    As[TILE * BK];        // 16 KB (fp32, swizzled)
  __shared__ _Float16 Bs[TILE * BK];        // 8 KB  (fp16, swizzled)
  __shared__ float rowsum[TILE];
  __shared__ float q_l[TILE];
  __shared__ float v_l[TILE];

  const int tid  = threadIdx.x;
  const int w    = tid >> 6;
  const int lane = tid & 63;

  // XCD-aware swizzle: the 8 blocks sharing an A M-tile have blockIdx
  // congruent mod 8 -> same XCD L2 -> A-tile fetched once per use-group.
  const int bm = ((blockIdx.x >> 6) << 3) | (blockIdx.x & 7);
  const int bn = (blockIdx.x >> 3) & 7;
  const int R0 = bm * TILE;
  const int C0 = bn * TILE;
  const int bidx = R0 >> 11;          // batch index (2048 rows per batch)

  if (tid < TILE) {
    q_l[tid] = q[(size_t)bidx * H_SZ + C0 + tid];
    v_l[tid] = v[C0 + tid];
    rowsum[tid] = 0.f;
  }

  const int wm = w >> 1, wn = w & 1;
  const int cL = lane & 15, quad = lane >> 4;

  floatx4 acc[4][4];
  #pragma unroll
  for (int m = 0; m < 4; ++m)
    #pragma unroll
    for (int n = 0; n < 4; ++n)
      acc[m][n] = (floatx4){0.f, 0.f, 0.f, 0.f};

  // ---- per-wave staging source pointers (advance by BK per kt) ----
  // A: issue j = w*4+i :  wm_j=j>>3, m_j=(j>>1)&3, h_j=j&1
  //    lane source: row = wm_j*64+m_j*16+cL, kflt = quad*8 + h_j*4
  const float* pA[4];
  #pragma unroll
  for (int i = 0; i < 4; ++i) {
    const int j = w * 4 + i;
    const int row = ((j >> 3) * 64) + (((j >> 1) & 3) * 16) + cL;
    const int kf  = quad * 8 + (j & 1) * 4;
    pA[i] = A + (size_t)(R0 + row) * H_SZ + kf;
  }
  // B: issue j = w + 4*i : wn_j=j>>2, n_j=j&3
  //    lane source: row = wn_j*64+n_j*16+cL, khalf = quad*8
  const _Float16* pB[2];
  #pragma unroll
  for (int i = 0; i < 2; ++i) {
    const int j = w + 4 * i;
    const int row = ((j >> 2) * 64) + ((j & 3) * 16) + cL;
    pB[i] = Bt + (size_t)(C0 + row) * H_SZ + quad * 8;
  }

  for (int kt = 0; kt < H_SZ / BK; ++kt) {
    __syncthreads();               // previous tile's compute done
    #pragma unroll
    for (int i = 0; i < 4; ++i) {
      const int j = w * 4 + i;
      gl_lds16(pA[i], (char*)As + j * 1024);
      pA[i] += BK;
    }
    #pragma unroll
    for (int i = 0; i < 2; ++i) {
      const int j = w + 4 * i;
      gl_lds16(pB[i], (char*)Bs + j * 1024);
      pB[i] += BK;
    }
    __syncthreads();               // drain staging

    half8 af[4], bf[4];
    #pragma unroll
    for (int m = 0; m < 4; ++m) {
      float4 lo = *(const float4*)((const char*)As + wm * 8192 + m * 2048 + lane * 16);
      float4 hi = *(const float4*)((const char*)As + wm * 8192 + m * 2048 + 1024 + lane * 16);
      half8 a;
      a[0] = (_Float16)lo.x; a[1] = (_Float16)lo.y;
      a[2] = (_Float16)lo.z; a[3] = (_Float16)lo.w;
      a[4] = (_Float16)hi.x; a[5] = (_Float16)hi.y;
      a[6] = (_Float16)hi.z; a[7] = (_Float16)hi.w;
      af[m] = a;
    }
    #pragma unroll
    for (int n = 0; n < 4; ++n)
      bf[n] = *(const half8*)((const char*)Bs + wn * 4096 + n * 1024 + lane * 16);
    #pragma unroll
    for (int m = 0; m < 4; ++m)
      #pragma unroll
      for (int n = 0; n < 4; ++n)
        acc[m][n] = __builtin_amdgcn_mfma_f32_16x16x32_f16(af[m], bf[n], acc[m][n], 0, 0, 0);
  }

  // ---- epilogue: v[n]*tanh(q+c), reduce over this block's 128 columns ----
  float qv[4], vv[4];
  #pragma unroll
  for (int n = 0; n < 4; ++n) {
    const int col = wn * 64 + n * 16 + cL;
    qv[n] = q_l[col];
    vv[n] = v_l[col];
  }
  // C/D layout: col = lane&15, row = quad*4 + reg
  #pragma unroll
  for (int m = 0; m < 4; ++m) {
    #pragma unroll
    for (int r = 0; r < 4; ++r) {
      float s = 0.f;
      #pragma unroll
      for (int n = 0; n < 4; ++n)
        s += vv[n] * fast_tanh(qv[n] + acc[m][n][r]);
      s += __shfl_xor(s, 1);
      s += __shfl_xor(s, 2);
      s += __shfl_xor(s, 4);
      s += __shfl_xor(s, 8);
      if (cL == 0)
        atomicAdd(&rowsum[wm * 64 + m * 16 + quad * 4 + r], s);
    }
  }
  __syncthreads();
  if (tid < TILE)
    partial[(size_t)bn * M_SZ + R0 + tid] = rowsum[tid];
}

// ---------------- masked softmax over S per batch row ----------------
__global__ __launch_bounds__(256) void softmax_kernel(
    const float* __restrict__ partial, const int* __restrict__ lengths,
    float* __restrict__ out) {
  __shared__ float wred[4];
  __shared__ float wsum[4];
  const int b = blockIdx.x;
  const int tid = threadIdx.x;
  const int len = lengths[b];

  float lg[8];
  #pragma unroll
  for (int i = 0; i < 8; ++i) {
    const int s = tid + i * 256;
    const size_t row = (size_t)b * S_SZ + s;
    float l = 0.f;
    #pragma unroll
    for (int nt = 0; nt < 8; ++nt) l += partial[(size_t)nt * M_SZ + row];
    lg[i] = (s < len) ? l : -INFINITY;
  }

  float mx = lg[0];
  #pragma unroll
  for (int i = 1; i < 8; ++i) mx = fmaxf(mx, lg[i]);
  #pragma unroll
  for (int off = 32; off; off >>= 1) mx = fmaxf(mx, __shfl_xor(mx, off));
  if ((tid & 63) == 0) wred[tid >> 6] = mx;
  __syncthreads();
  mx = fmaxf(fmaxf(wred[0], wred[1]), fmaxf(wred[2], wred[3]));

  float pe[8];
  float sum = 0.f;
  #pragma unroll
  for (int i = 0; i < 8; ++i) {
    float e = (lg[i] == -INFINITY) ? 0.f : __expf(lg[i] - mx);
    pe[i] = e;
    sum += e;
  }
  #pragma unroll
  for (int off = 32; off; off >>= 1) sum += __shfl_xor(sum, off);
  if ((tid & 63) == 0) wsum[tid >> 6] = sum;
  __syncthreads();
  sum = wsum[0] + wsum[1] + wsum[2] + wsum[3];
  const float inv = 1.0f / sum;

  #pragma unroll
  for (int i = 0; i < 8; ++i) {
    const int s = tid + i * 256;
    out[(size_t)b * S_SZ + s] = pe[i] * inv;
  }
}

extern "C" void kernel_launch(void* const* d_in, const int* in_sizes, int n_in,
                              void* d_out, int out_size, void* d_ws, size_t ws_size,
                              hipStream_t stream) {
  const float* hidden  = (const float*)d_in[0];  // (32, 1024)
  const float* enc     = (const float*)d_in[1];  // (32, 2048, 1024)
  const int*   lengths = (const int*)d_in[2];    // (32,)
  const float* Wq      = (const float*)d_in[3];  // (1024, 1024)
  const float* Wk      = (const float*)d_in[4];  // (1024, 1024)
  const float* v       = (const float*)d_in[5];  // (1024,)
  float* out = (float*)d_out;                    // (32, 2048) fp32

  // ws layout: B16 (2 MB) | q (128 KB) | partial (2 MB)
  char* ws = (char*)d_ws;
  _Float16* B16     = (_Float16*)ws;
  float*    q       = (float*)(ws + 2097152);
  float*    partial = (float*)(ws + 2097152 + 131072);

  convert_f32_to_f16<<<1024, 256, 0, stream>>>(Wk, (h4*)B16, (H_SZ * H_SZ) / 4);
  query_kernel<<<8192, 256, 0, stream>>>(hidden, Wq, q);
  fused_keys_kernel<<<(M_SZ / TILE) * (H_SZ / TILE), 256, 0, stream>>>(enc, B16, q, v, partial);
  softmax_kernel<<<B_SZ, 256, 0, stream>>>(partial, lengths, out);
}